// Round 2
// baseline (10171.874 us; speedup 1.0000x reference)
//
#include <hip/hip_runtime.h>

#define B_ 2048
#define T_ 48
#define V_ 59
#define H_ 512
#define KP_ 640   // padded K for gates GEMM: [ximp 0..58 | 0 | mask 64..122 | 0 | h 128..639]
#define G4_ 2048  // 4*H
#define NBLK_ 128
#define RPB_ 16   // batch rows per block

typedef __bf16 bf16x8 __attribute__((ext_vector_type(8)));
typedef float f32x4 __attribute__((ext_vector_type(4)));

__device__ __forceinline__ unsigned short f2bf(float x){
  union { float f; unsigned u; } v; v.f = x;
  unsigned r = (v.u + 0x7FFFu + ((v.u >> 16) & 1u)) >> 16;
  return (unsigned short)r;
}
__device__ __forceinline__ float bf2f(unsigned short u){
  union { unsigned u; float f; } v; v.u = ((unsigned)u) << 16; return v.f;
}
__device__ __forceinline__ float sigf(float x){ return 1.f/(1.f+expf(-x)); }

// swizzled element offset inside A_lds [16 rows][640 bf16], 16B-chunk xor (row&7)
__device__ __forceinline__ int a_elem(int row, int colk){
  return row*640 + ((((colk>>3) ^ (row&7)))<<3) + (colk&7);
}

// ---- workspace layout (bytes) ----
static const size_t OFF_LN   = 0;                      // loss_num[48]
static const size_t OFF_LD   = 256;                    // loss_den[48]
static const size_t MEMSET_BYTES = 512;
static const size_t OFF_WGTR = 512;                    // WgTr bf16, permuted+swizzled [40 stages][512][8][8] = 2621440 B
static const size_t OFF_WGHB = OFF_WGTR + 2621440;     // Wghb bf16 [512][64] = 65536 B
static const size_t OFF_WHB  = OFF_WGHB + 65536;       // WhB  bf16 [64][512] = 65536 B
static const size_t OFF_WFR  = OFF_WHB  + 65536;       // WfrT f32 [59][59] = 14080 B
static const size_t OFF_BETA = OFF_WFR  + 14080;       // beta f32 [B*T*V]

// ------------------- init: transposes / packing -------------------
__global__ void init_k(const float* __restrict__ W_gh, const float* __restrict__ W_hist,
                       const float* __restrict__ W_fr,
                       const float* __restrict__ W_ih, const float* __restrict__ W_hh,
                       unsigned short* __restrict__ Wghb, unsigned short* __restrict__ WhB,
                       float* __restrict__ WfrT, unsigned short* __restrict__ WgTr)
{
  int tid = blockIdx.x*blockDim.x + threadIdx.x;
  int nt  = gridDim.x*blockDim.x;
  // Wghb[n][k] = bf16(W_gh[n][k]) for k<59 else 0   (B-operand for gamma_h MFMA)
  for (int i = tid; i < H_*64; i += nt){ int n = i >> 6, k = i & 63; Wghb[i] = (k < V_) ? f2bf(W_gh[n*V_ + k]) : (unsigned short)0; }
  // WhB[v][k] = bf16(W_hist[v][k]) for v<59 else 0  (B-operand for x_h MFMA)
  for (int i = tid; i < 64*H_; i += nt){ int n = i >> 9; WhB[i] = (n < V_) ? f2bf(W_hist[i]) : (unsigned short)0; }
  // WfrT[u][v] = (u==v) ? 0 : W_fr[v][u]
  for (int i = tid; i < V_*V_; i += nt){ int u = i / V_, v = i - u*V_; WfrT[i] = (u==v) ? 0.f : W_fr[v*V_ + u]; }
  // WgTr: permuted + pre-swizzled gates weight.
  // slot ii = ((stg*512 + r)*8 + cpos)*8 + j ; stg = p*10+s ; r = g*128 + ul ;
  // holds Wfull[n = g*512 + p*128 + ul][k = s*64 + ((cpos ^ (r&7))<<3) + j]
  // Wfull k-map: k<59 -> W_ih[n][k]; 64<=k<123 -> W_ih[n][59+k-64]; 128<=k -> W_hh[n][k-128]; else 0
  for (int i = tid; i < (40<<15); i += nt){
    int j    = i & 7;
    int cpos = (i >> 3) & 7;
    int r    = (i >> 6) & 511;
    int stg  = i >> 15;
    int p = stg / 10, s = stg - p*10;
    int n = ((r >> 7) << 9) + p*128 + (r & 127);
    int k = s*64 + (((cpos ^ (r & 7)) << 3)) + j;
    float v = 0.f;
    if (k < V_)           v = W_ih[n*(2*V_) + k];
    else if (k >= 64 && k < 123) v = W_ih[n*(2*V_) + V_ + (k - 64)];
    else if (k >= 128)    v = W_hh[n*H_ + (k - 128)];
    WgTr[i] = f2bf(v);
  }
}

// ------------------- beta + loss-den precompute (recurrence-independent) -------------------
__global__ __launch_bounds__(256) void beta_k(
    const float* __restrict__ mk, const float* __restrict__ dl,
    const float* __restrict__ w_gx, const float* __restrict__ b_gx,
    const float* __restrict__ W_wc, const float* __restrict__ b_wc,
    float* __restrict__ beta_pre, float* __restrict__ loss_den)
{
  __shared__ float gx[4][64], mm[4][64];
  const int tid = threadIdx.x;
  const int rw  = tid >> 6, v = tid & 63;
  const int row = blockIdx.x*4 + rw;           // row = b*T + t
  size_t base = (size_t)row * V_;
  float m = 0.f, g = 0.f;
  if (v < V_){
    float d = dl[base+v];
    m = mk[base+v];
    g = expf(-fmaxf(d*w_gx[v]+b_gx[v], 0.f));
  }
  gx[rw][v] = g; mm[rw][v] = m;
  __syncthreads();
  if (v < V_){
    float bt = b_wc[v];
    const float* wr = W_wc + (size_t)v*(2*V_);
    for (int u = 0; u < V_; ++u)
      bt += gx[rw][u]*wr[u] + mm[rw][u]*wr[V_+u];
    beta_pre[base+v] = bt;
  }
  float s = m;
#pragma unroll
  for (int off=32; off; off>>=1) s += __shfl_down(s, off);
  if (v == 0){
    int t = row % T_;
    atomicAdd(&loss_den[t], s);
  }
}

// ------------------- persistent-per-block fused kernel: zero inter-block sync -------------------
__global__ __launch_bounds__(512,1) void fused(
    const float* __restrict__ x, const float* __restrict__ mk, const float* __restrict__ dl,
    const float* __restrict__ b_gh, const float* __restrict__ b_hist, const float* __restrict__ b_fr,
    const unsigned short* __restrict__ Wghb, const unsigned short* __restrict__ WhB,
    const float* __restrict__ WfrT, const float* __restrict__ beta_pre,
    const unsigned short* __restrict__ WgTr,
    const float* __restrict__ b_ih, const float* __restrict__ b_hh,
    float* loss_num,
    float* __restrict__ out_ximp, float* __restrict__ out_hid)
{
  // LDS: [ A 20480 | B0 65536 | B1 65536 (aliases phase-1 scratch) ] = 151552 B
  __shared__ __align__(16) unsigned char SMEM[151552];
  unsigned short* A_lds = (unsigned short*)SMEM;
  uint4* Bbuf0 = (uint4*)(SMEM + 20480);
  uint4* Bbuf1 = (uint4*)(SMEM + 86016);
  unsigned short* d_bf = (unsigned short*)(SMEM + 86016);   // [16][64] bf16, swizzled
  float* m_s  = (float*)(SMEM + 88064);
  float* x_s  = m_s  + 1024;
  float* xh_s = x_s  + 1024;
  float* xr_s = xh_s + 1024;
  float* bt_s = xr_s + 1024;
  float* red  = bt_s + 1024;   // 8 floats

  const int tid  = threadIdx.x;
  const int blk  = blockIdx.x;
  const int r1   = blk * RPB_;
  const int w    = tid >> 6;
  const int lane = tid & 63;
  const int col  = lane & 15;
  const int quad = lane >> 4;
  const int w16c = w*16 + col;
  const int x7   = col & 7;
  const uint4* WgTr4 = (const uint4*)WgTr;

  // t-invariant per-thread constants
  float bghv[4];
#pragma unroll
  for (int i=0;i<4;++i) bghv[i] = b_gh[(w*4+i)*16 + col];
  float bhv = 0.f;
  if (w < 4){ int v = w*16+col; bhv = (v < V_) ? b_hist[v] : 0.f; }
  float bi[4], bfv[4], bgv[4], bov[4];
#pragma unroll
  for (int p=0;p<4;++p){
    int u = p*128 + w16c;
    bi[p]  = b_ih[u]        + b_hh[u];
    bfv[p] = b_ih[H_+u]     + b_hh[H_+u];
    bgv[p] = b_ih[2*H_+u]   + b_hh[2*H_+u];
    bov[p] = b_ih[3*H_+u]   + b_hh[3*H_+u];
  }
  float creg[4][4];
#pragma unroll
  for (int p=0;p<4;++p)
#pragma unroll
    for (int r=0;r<4;++r) creg[p][r] = 0.f;

  // zero A (covers h=0 at t=0 and the permanent zero pad columns)
  for (int i = tid; i < 16*640; i += 512) A_lds[i] = 0;
  __syncthreads();

  for (int t = 0; t < T_; ++t){
    // prefetch gates-weight stage 0 into registers (consumed after phase 1)
    uint4 st[8];
#pragma unroll
    for (int it=0; it<8; ++it) st[it] = WgTr4[it*512 + tid];

    // ---- load inputs for this t ----
    for (int i2 = tid; i2 < RPB_*V_; i2 += 512){
      int b = i2 / V_, v = i2 - b*V_;
      size_t g = ((size_t)(r1+b)*T_ + t)*V_ + v;
      float mm2 = mk[g], xx = x[g], dd = dl[g];
      m_s[b*64+v] = mm2; x_s[b*64+v] = xx; bt_s[b*64+v] = beta_pre[g];
      d_bf[b*64 + (((v>>3) ^ (b&7))<<3) + (v&7)] = f2bf(dd);
      A_lds[a_elem(b, 64+v)] = f2bf(mm2);          // mask column of A
    }
    __syncthreads();

    // ---- gamma_h via MFMA (d[16x64] @ Wghb^T), then h~ = h*gamma in place ----
#pragma unroll
    for (int i=0;i<4;++i){
      f32x4 ac = (f32x4)(0.f);
      int u0 = (w*4+i)*16 + col;
      const unsigned short* wb = Wghb + (size_t)u0*64;
#pragma unroll
      for (int kk=0; kk<2; ++kk){
        bf16x8 a  = *(const bf16x8*)&d_bf[col*64 + (((kk*4+quad) ^ x7)<<3)];
        bf16x8 bb = *(const bf16x8*)&wb[kk*32 + quad*8];
        ac = __builtin_amdgcn_mfma_f32_16x16x32_bf16(a, bb, ac, 0, 0, 0);
      }
      float bg = bghv[i];
#pragma unroll
      for (int r=0;r<4;++r){
        int b = quad*4 + r;
        float gm = expf(-fmaxf(ac[r]+bg, 0.f));
        int eo = a_elem(b, 128+u0);
        A_lds[eo] = f2bf(bf2f(A_lds[eo]) * gm);
      }
    }
    __syncthreads();

    // ---- x_h = h~ @ W_hist^T (waves 0..3) ----
    if (w < 4){
      f32x4 ac = (f32x4)(0.f);
      const unsigned short* wb = WhB + (size_t)(w*16+col)*H_;
#pragma unroll
      for (int kk=0; kk<16; ++kk){
        bf16x8 a  = *(const bf16x8*)&A_lds[col*640 + (((16 + kk*4 + quad) ^ x7)<<3)];
        bf16x8 bb = *(const bf16x8*)&wb[kk*32 + quad*8];
        ac = __builtin_amdgcn_mfma_f32_16x16x32_bf16(a, bb, ac, 0, 0, 0);
      }
      int v = w*16+col;
#pragma unroll
      for (int r=0;r<4;++r) xh_s[(quad*4+r)*64 + v] = ac[r] + bhv;
    }
    __syncthreads();

    // ---- x_r ----
#pragma unroll
    for (int it=0; it<2; ++it){
      int b = (tid>>6) + it*8, v = lane;
      if (v < V_){
        float mm2 = m_s[b*64+v];
        xr_s[b*64+v] = mm2*x_s[b*64+v] + (1.f-mm2)*xh_s[b*64+v];
      }
    }
    __syncthreads();

    // ---- feature regression + combine + loss ----
    float num = 0.f;
#pragma unroll
    for (int it=0; it<2; ++it){
      int b = (tid>>6) + it*8, v = lane;
      if (v < V_){
        float xu = b_fr[v];
        for (int u=0; u<V_; ++u) xu += xr_s[b*64+u]*WfrT[u*V_+v];
        float bt = bt_s[b*64+v];
        float xh = xh_s[b*64+v];
        float xc = bt*xu + (1.f-bt)*xh;
        float mm2 = m_s[b*64+v], xx = x_s[b*64+v];
        num += fabsf(xx - xc)*mm2;
        float xi = mm2*xx + (1.f-mm2)*xc;
        out_ximp[((size_t)(r1+b)*T_ + t)*V_ + v] = xi;
        A_lds[a_elem(b, v)] = f2bf(xi);
      }
    }
#pragma unroll
    for (int off=32; off; off>>=1) num += __shfl_down(num, off);
    if (lane == 0) red[w] = num;
    __syncthreads();
    if (tid == 0){
      float n = 0.f;
#pragma unroll
      for (int i=0;i<8;++i) n += red[i];
      atomicAdd(&loss_num[t], n);
    }

    // commit prefetched stage 0 (scratch region is dead from here on)
#pragma unroll
    for (int it=0; it<8; ++it) Bbuf0[it*512 + tid] = st[it];
    __syncthreads();

    // ---- gates GEMM: M=16, N=2048, K=640 ; 40 double-buffered stages ----
    f32x4 acc2[4][4];
#pragma unroll
    for (int p=0;p<4;++p)
#pragma unroll
      for (int g=0;g<4;++g) acc2[p][g] = (f32x4)(0.f);

    int cur = 0;
#pragma unroll
    for (int p=0; p<4; ++p){
#pragma unroll 1
      for (int s=0; s<10; ++s){
        int ist = p*10 + s;
        if (ist < 39){
          const uint4* gs = WgTr4 + (size_t)(ist+1)*4096;
#pragma unroll
          for (int it=0; it<8; ++it) st[it] = gs[it*512 + tid];
        }
        const uint4* Bc = cur ? Bbuf1 : Bbuf0;
        bf16x8 af0 = *(const bf16x8*)&A_lds[col*640 + (((s*8 + quad)     ^ x7)<<3)];
        bf16x8 af1 = *(const bf16x8*)&A_lds[col*640 + (((s*8 + 4 + quad) ^ x7)<<3)];
#pragma unroll
        for (int g=0; g<4; ++g){
          int rbase = g*1024 + w16c*8;
          bf16x8 b0 = *(const bf16x8*)&Bc[rbase + (quad ^ x7)];
          bf16x8 b1 = *(const bf16x8*)&Bc[rbase + ((4 + quad) ^ x7)];
          acc2[p][g] = __builtin_amdgcn_mfma_f32_16x16x32_bf16(af0, b0, acc2[p][g], 0, 0, 0);
          acc2[p][g] = __builtin_amdgcn_mfma_f32_16x16x32_bf16(af1, b1, acc2[p][g], 0, 0, 0);
        }
        if (ist < 39){
          uint4* Bn = cur ? Bbuf0 : Bbuf1;
#pragma unroll
          for (int it=0; it<8; ++it) Bn[it*512 + tid] = st[it];
        }
        __syncthreads();
        cur ^= 1;
      }
    }

    // ---- LSTM epilogue: c in regs, h(t) -> A_lds h-slot (bf16) + out_hid ----
#pragma unroll
    for (int p=0; p<4; ++p){
      int u = p*128 + w16c;
#pragma unroll
      for (int r=0; r<4; ++r){
        int br = quad*4 + r;
        float gi = acc2[p][0][r] + bi[p];
        float gf = acc2[p][1][r] + bfv[p];
        float gg = acc2[p][2][r] + bgv[p];
        float go = acc2[p][3][r] + bov[p];
        float cn = sigf(gf)*creg[p][r] + sigf(gi)*tanhf(gg);
        float hn = sigf(go)*tanhf(cn);
        creg[p][r] = cn;
        A_lds[a_elem(br, 128+u)] = f2bf(hn);
        out_hid[((size_t)(r1+br)*T_ + t)*H_ + u] = hn;
      }
    }
    __syncthreads();
  }
}

// ------------------- final loss reduction -------------------
__global__ void loss_k(const float* __restrict__ loss_num, const float* __restrict__ loss_den,
                       float* __restrict__ out_loss)
{
  int tid = threadIdx.x;
  float v = 0.f;
  if (tid < T_) v = loss_num[tid]/(loss_den[tid] + 1e-5f);
#pragma unroll
  for (int off=32; off; off>>=1) v += __shfl_down(v, off);
  if (tid == 0) *out_loss = v;
}

extern "C" void kernel_launch(void* const* d_in, const int* in_sizes, int n_in,
                              void* d_out, int out_size, void* d_ws, size_t ws_size,
                              hipStream_t stream)
{
  const float* x      = (const float*)d_in[0];
  const float* mk     = (const float*)d_in[1];
  const float* dl     = (const float*)d_in[2];
  const float* W_gh   = (const float*)d_in[3];
  const float* b_gh   = (const float*)d_in[4];
  const float* w_gx   = (const float*)d_in[5];
  const float* b_gx   = (const float*)d_in[6];
  const float* W_hist = (const float*)d_in[7];
  const float* b_hist = (const float*)d_in[8];
  const float* W_fr   = (const float*)d_in[9];
  const float* b_fr   = (const float*)d_in[10];
  const float* W_wc   = (const float*)d_in[11];
  const float* b_wc   = (const float*)d_in[12];
  const float* W_ih   = (const float*)d_in[13];
  const float* W_hh   = (const float*)d_in[14];
  const float* b_ih   = (const float*)d_in[15];
  const float* b_hh   = (const float*)d_in[16];

  char* ws = (char*)d_ws;
  float*          lnum = (float*)(ws + OFF_LN);
  float*          lden = (float*)(ws + OFF_LD);
  unsigned short* WgTr = (unsigned short*)(ws + OFF_WGTR);
  unsigned short* Wghb = (unsigned short*)(ws + OFF_WGHB);
  unsigned short* WhB  = (unsigned short*)(ws + OFF_WHB);
  float*          WfrT = (float*)(ws + OFF_WFR);
  float*          beta = (float*)(ws + OFF_BETA);

  float* out      = (float*)d_out;
  float* out_ximp = out;                                   // [B,T,V]
  float* out_loss = out + (size_t)B_*T_*V_;                // scalar
  float* out_hid  = out + (size_t)B_*T_*V_ + 1;            // [B,T,H]

  hipMemsetAsync(d_ws, 0, MEMSET_BYTES, stream);           // loss accumulators
  init_k<<<2048, 256, 0, stream>>>(W_gh, W_hist, W_fr, W_ih, W_hh,
                                   Wghb, WhB, WfrT, WgTr);
  beta_k<<<(B_*T_)/4, 256, 0, stream>>>(mk, dl, w_gx, b_gx, W_wc, b_wc, beta, lden);
  fused<<<NBLK_, 512, 0, stream>>>(x, mk, dl, b_gh, b_hist, b_fr,
                                   Wghb, WhB, WfrT, beta, WgTr, b_ih, b_hh,
                                   lnum, out_ximp, out_hid);
  loss_k<<<1, 64, 0, stream>>>(lnum, lden, out_loss);
}

// Round 4
// 4236.107 us; speedup vs baseline: 2.4012x; 2.4012x over previous
//
#include <hip/hip_runtime.h>

#define B_ 2048
#define T_ 48
#define V_ 59
#define H_ 512
#define KP_ 640   // A cols: [ximp 0..58 | mask 59..117 | h 118..629 | pad 630..639]
#define NBLK_ 256
#define RG_ 32    // phase-2 row-groups (64 rows each)
#define UG_ 8     // phase-2 unit-groups (64 units each); ug == XCD (blk%8)

typedef __bf16 bf16x8 __attribute__((ext_vector_type(8)));
typedef float f32x4 __attribute__((ext_vector_type(4)));

__device__ __forceinline__ unsigned short f2bf(float x){
  union { float f; unsigned u; } v; v.f = x;
  unsigned r = (v.u + 0x7FFFu + ((v.u >> 16) & 1u)) >> 16;
  return (unsigned short)r;
}
__device__ __forceinline__ float sigf(float x){ return 1.f/(1.f+expf(-x)); }

// ---- coherent (cross-XCD) access helpers: relaxed agent-scope atomics ----
// These bypass the non-coherent per-XCD L2 per access; NO cache-wide fences.
__device__ __forceinline__ unsigned cload(const unsigned* p){
  return __hip_atomic_load(p, __ATOMIC_RELAXED, __HIP_MEMORY_SCOPE_AGENT);
}
__device__ __forceinline__ unsigned long long cload64(const unsigned long long* p){
  return __hip_atomic_load(p, __ATOMIC_RELAXED, __HIP_MEMORY_SCOPE_AGENT);
}
__device__ __forceinline__ void cstore(unsigned* p, unsigned v){
  __hip_atomic_store(p, v, __ATOMIC_RELAXED, __HIP_MEMORY_SCOPE_AGENT);
}
__device__ __forceinline__ float cloadf(const float* p){
  union { unsigned u; float f; } c; c.u = cload((const unsigned*)p); return c.f;
}
__device__ __forceinline__ void cstoref(float* p, float v){
  union { float f; unsigned u; } c; c.f = v; cstore((unsigned*)p, c.u);
}

// producer/consumer flags (monotonic counters). post: drain vmem, block-sync, add.
__device__ __forceinline__ void post_flag(unsigned* f){
  asm volatile("s_waitcnt vmcnt(0)" ::: "memory");   // my wave's coherent stores done
  __syncthreads();                                    // all waves drained
  if (threadIdx.x == 0)
    __hip_atomic_fetch_add(f, 1u, __ATOMIC_RELAXED, __HIP_MEMORY_SCOPE_AGENT);
}
__device__ __forceinline__ void wait_flag(unsigned* f, unsigned tgt){
  if (threadIdx.x == 0){
    while (cload(f) < tgt) __builtin_amdgcn_s_sleep(2);
  }
  __syncthreads();
}

// ---- workspace layout (bytes) ----
static const size_t OFF_H    = 0;                      // h fp32 [2048*512] = 4 MB
static const size_t OFF_LN   = 4194304;                // loss_num[48]
static const size_t OFF_LD   = OFF_LN + 256;           // loss_den[48]
static const size_t OFF_F1   = OFF_LD + 256;           // flags1[32]
static const size_t OFF_F2   = OFF_F1 + 256;           // flags2[32]
static const size_t OFF_A    = OFF_F2 + 256;           // A bf16 [2048*640] = 2621440
static const size_t MEMSET_BYTES = OFF_A + (size_t)B_*KP_*2;   // 6816768
static const size_t OFF_WGT  = MEMSET_BYTES;           // WgT bf16 [2048*640]
static const size_t OFF_WGHB = OFF_WGT + (size_t)4*H_*KP_*2;   // Wghb bf16 [512][64]
static const size_t OFF_WHB  = OFF_WGHB + 65536;       // WhB bf16 [64][512]
static const size_t OFF_WFR  = OFF_WHB + 65536;        // WfrT f32 [59][59]
static const size_t OFF_BETA = OFF_WFR + 14080;        // beta f32 [B*T*V]

// ------------------- init: transposes / packing -------------------
__global__ void init_k(const float* __restrict__ W_gh, const float* __restrict__ W_hist,
                       const float* __restrict__ W_fr,
                       const float* __restrict__ W_ih, const float* __restrict__ W_hh,
                       unsigned short* __restrict__ Wghb, unsigned short* __restrict__ WhB,
                       float* __restrict__ WfrT, unsigned short* __restrict__ WgT)
{
  int tid = blockIdx.x*blockDim.x + threadIdx.x;
  int nt  = gridDim.x*blockDim.x;
  // Wghb[j][k] = bf16(W_gh[j][k]) for k<59 else 0 (B-operand for gamma_h MFMA)
  for (int i = tid; i < H_*64; i += nt){ int j = i >> 6, k = i & 63; Wghb[i] = (k < V_) ? f2bf(W_gh[j*V_ + k]) : (unsigned short)0; }
  // WhB[v][k] = bf16(W_hist[v][k]) for v<59 else 0
  for (int i = tid; i < 64*H_; i += nt){ int n = i >> 9; WhB[i] = (n < V_) ? f2bf(W_hist[i]) : (unsigned short)0; }
  // WfrT[u][v] = (u==v) ? 0 : W_fr[v][u]
  for (int i = tid; i < V_*V_; i += nt){ int u = i / V_, v = i - u*V_; WfrT[i] = (u==v) ? 0.f : W_fr[v*V_ + u]; }
  // WgT[n*640+k]: n = gate*512+unit. k<118 -> W_ih[n][k]; 118<=k<630 -> W_hh[n][k-118]; else 0
  for (int i = tid; i < 4*H_*KP_; i += nt){
    int n = i / KP_, k = i - n*KP_;
    float v = 0.f;
    if (k < 2*V_)      v = W_ih[n*(2*V_) + k];
    else if (k < 630)  v = W_hh[n*H_ + (k-118)];
    WgT[i] = f2bf(v);
  }
}

// ------------------- beta + loss-den precompute (recurrence-independent) -------------------
__global__ __launch_bounds__(256) void beta_k(
    const float* __restrict__ mk, const float* __restrict__ dl,
    const float* __restrict__ w_gx, const float* __restrict__ b_gx,
    const float* __restrict__ W_wc, const float* __restrict__ b_wc,
    float* __restrict__ beta_pre, float* __restrict__ loss_den)
{
  __shared__ float gx[4][64], mm[4][64];
  const int tid = threadIdx.x;
  const int rw  = tid >> 6, v = tid & 63;
  const int row = blockIdx.x*4 + rw;           // row = b*T + t
  size_t base = (size_t)row * V_;
  float m = 0.f, g = 0.f;
  if (v < V_){
    float d = dl[base+v];
    m = mk[base+v];
    g = expf(-fmaxf(d*w_gx[v]+b_gx[v], 0.f));
  }
  gx[rw][v] = g; mm[rw][v] = m;
  __syncthreads();
  if (v < V_){
    float bt = b_wc[v];
    const float* wr = W_wc + (size_t)v*(2*V_);
    for (int u = 0; u < V_; ++u)
      bt += gx[rw][u]*wr[u] + mm[rw][u]*wr[V_+u];
    beta_pre[base+v] = bt;
  }
  float s = m;
#pragma unroll
  for (int off=32; off; off>>=1) s += __shfl_down(s, off);
  if (v == 0){
    int t = row % T_;
    atomicAdd(&loss_den[t], s);
  }
}

// ------------------- persistent fused kernel: flag-based P/C sync, no fences -------------------
__global__ __launch_bounds__(512,2) void fused(
    const float* __restrict__ x, const float* __restrict__ mk, const float* __restrict__ dl,
    const float* __restrict__ b_gh, const float* __restrict__ b_hist, const float* __restrict__ b_fr,
    const unsigned short* __restrict__ Wghb, const unsigned short* __restrict__ WhB,
    const float* __restrict__ WfrT, const float* __restrict__ beta_pre,
    const unsigned short* __restrict__ WgT,
    const float* __restrict__ b_ih, const float* __restrict__ b_hh,
    float* h_ws, unsigned* A_dw, unsigned* flags1, unsigned* flags2,
    float* loss_num, const float* loss_den,
    float* __restrict__ out_ximp, float* __restrict__ out_hid, float* __restrict__ out_loss)
{
  // 88 KiB LDS -> exactly 1 block/CU, guaranteeing 256 co-resident blocks.
  __shared__ __align__(16) unsigned char SMEM[90112];
  // phase-2 view
  uint4* ldsA = (uint4*)SMEM;                          // [2][64*8]
  uint4* ldsB = (uint4*)(SMEM + 16384);                // [2][256*8]
  // phase-1 view (aliases; phases separated by syncs)
  unsigned short* d_bf = (unsigned short*)SMEM;        // [16][64] swizzled
  float* m_s  = (float*)(SMEM + 2048);
  float* x_s  = (float*)(SMEM + 4096);
  float* xh_s = (float*)(SMEM + 6144);
  float* xr_s = (float*)(SMEM + 8192);
  float* gm_s = (float*)(SMEM + 10240);                // [8][512]
  unsigned short* hA = (unsigned short*)(SMEM + 26624);// [16][520]
  unsigned short* im = (unsigned short*)(SMEM + 43264);// [8][120]
  float* red  = (float*)(SMEM + 45184);                // [8]

  const int tid  = threadIdx.x;
  const int blk  = blockIdx.x;
  const int r1   = blk * 8;            // phase-1 rows
  const int rg   = blk >> 3;           // row-group (64 rows)
  const int ug   = blk & 7;            // unit-group (64 units) == XCD
  const int r2   = rg * 64;
  const int u0   = ug * 64;
  const int w    = tid >> 6;
  const int lane = tid & 63;
  const int col  = lane & 15;
  const int quad = lane >> 4;
  const int x7   = col & 7;
  const int rw2  = w >> 2;             // phase-2 row half
  const int uh   = w & 3;              // phase-2 unit 16-group

  // t-invariant constants
  float bghv[4];
#pragma unroll
  for (int i=0;i<4;++i) bghv[i] = b_gh[(w*4+i)*16 + col];
  float bhv = 0.f;
  if (w < 4){ int v = w*16+col; bhv = (v < V_) ? b_hist[v] : 0.f; }
  const int u2 = u0 + uh*16 + col;     // phase-2 unit owned by this thread
  const float bi  = b_ih[u2]      + b_hh[u2];
  const float bfv = b_ih[H_+u2]   + b_hh[H_+u2];
  const float bgv = b_ih[2*H_+u2] + b_hh[2*H_+u2];
  const float bov = b_ih[3*H_+u2] + b_hh[3*H_+u2];
  float creg[2][4];
#pragma unroll
  for (int i=0;i<2;++i)
#pragma unroll
    for (int r=0;r<4;++r) creg[i][r] = 0.f;

  // phase-2 staging constants
  const int sr = tid >> 3, sc = tid & 7;               // A row / chunk
  const size_t aRowBase = (size_t)(r2+sr)*320;         // A_dw dword base of row
  const int aDst = sr*8 + (sc ^ (sr&7));
  size_t ngBase[4]; int bDst[4];
#pragma unroll
  for (int p=0;p<4;++p){
    ngBase[p] = (size_t)(p*H_ + u0 + sr)*80 + sc;      // uint4 idx into WgT
    bDst[p]   = (p*64 + sr)*8 + (sc ^ (sr&7));
  }
  const uint4* WgT4 = (const uint4*)WgT;
  const unsigned long long* A64 = (const unsigned long long*)A_dw;

#pragma unroll 1
  for (int t = 0; t < T_; ++t){
    // ================= phase 1 (rows r1..r1+8) =================
    {
      int b = tid >> 6, v = tid & 63;
      int dslot = b*64 + (((v>>3) ^ (b&7))<<3) + (v&7);
      if (v < V_){
        size_t g = ((size_t)(r1+b)*T_ + t)*V_ + v;
        float mm2 = mk[g], xx = x[g], dd = dl[g];
        m_s[b*64+v] = mm2; x_s[b*64+v] = xx;
        d_bf[dslot] = f2bf(dd);
        im[b*120 + 59 + v] = f2bf(mm2);
      } else d_bf[dslot] = 0;
    }
    __syncthreads();

    // gamma_h via MFMA: D[8 rows][512 units]; each wave 4 unit-tiles
#pragma unroll
    for (int i=0;i<4;++i){
      f32x4 ac = (f32x4)(0.f);
      int ub = (w*4+i)*16;
      const unsigned short* wb = Wghb + (size_t)(ub+col)*64;
#pragma unroll
      for (int kk=0;kk<2;++kk){
        bf16x8 a  = *(const bf16x8*)&d_bf[col*64 + (((kk*4+quad) ^ x7)<<3)];
        bf16x8 bb = *(const bf16x8*)&wb[kk*32 + quad*8];
        ac = __builtin_amdgcn_mfma_f32_16x16x32_bf16(a, bb, ac, 0, 0, 0);
      }
      if (quad < 2){
        float bg = bghv[i];
#pragma unroll
        for (int r=0;r<4;++r)
          gm_s[(quad*4+r)*H_ + ub + col] = expf(-fmaxf(ac[r]+bg, 0.f));
      }
    }
    // wait for h(t-1) producers (phase-2 of my rowgroup); also publishes gm_s
    if (t) wait_flag(&flags2[rg], 8u*(unsigned)t);
    else   __syncthreads();

    // h~ = h * gamma  (coherent h read; hA for x_h MFMA + later A-publish)
    {
      int j = tid;
#pragma unroll
      for (int b=0;b<8;++b){
        float hv = cloadf(&h_ws[(size_t)(r1+b)*H_ + j]) * gm_s[b*H_ + j];
        hA[b*520 + j] = f2bf(hv);
      }
    }
    __syncthreads();

    // x_h = h~ @ W_hist^T (waves 0..3)
    if (w < 4){
      f32x4 ac = (f32x4)(0.f);
      const unsigned short* wb = WhB + (size_t)(w*16+col)*H_;
#pragma unroll
      for (int kk=0;kk<16;++kk){
        bf16x8 a  = *(const bf16x8*)&hA[col*520 + kk*32 + quad*8];
        bf16x8 bb = *(const bf16x8*)&wb[kk*32 + quad*8];
        ac = __builtin_amdgcn_mfma_f32_16x16x32_bf16(a, bb, ac, 0, 0, 0);
      }
      if (quad < 2){
        int v = w*16+col;
#pragma unroll
        for (int r=0;r<4;++r) xh_s[(quad*4+r)*64 + v] = ac[r] + bhv;
      }
    }
    __syncthreads();

    // x_r
    {
      int b = w, v = lane;
      if (v < V_){
        float mm2 = m_s[b*64+v];
        xr_s[b*64+v] = mm2*x_s[b*64+v] + (1.f-mm2)*xh_s[b*64+v];
      }
    }
    __syncthreads();

    // feature regression + combine + x_imp + loss
    float num = 0.f;
    {
      int b = w, v = lane;
      if (v < V_){
        float xu = b_fr[v];
        for (int u=0; u<V_; ++u) xu += xr_s[b*64+u]*WfrT[u*V_+v];
        float bt = beta_pre[((size_t)(r1+b)*T_ + t)*V_ + v];
        float xh = xh_s[b*64+v];
        float xc = bt*xu + (1.f-bt)*xh;
        float mm2 = m_s[b*64+v], xx = x_s[b*64+v];
        num = fabsf(xx - xc)*mm2;
        float xi = mm2*xx + (1.f-mm2)*xc;
        __builtin_nontemporal_store(xi, &out_ximp[((size_t)(r1+b)*T_ + t)*V_ + v]);
        im[b*120 + v] = f2bf(xi);
      }
    }
#pragma unroll
    for (int off=32; off; off>>=1) num += __shfl_down(num, off);
    if (lane == 0) red[w] = num;
    __syncthreads();
    if (tid == 0){
      float n = 0.f;
#pragma unroll
      for (int i=0;i<8;++i) n += red[i];
      atomicAdd(&loss_num[t], n);
    }
    // publish A rows (coherent, dword-packed): [ximp|mask] then h~
    if (tid < 8*59){
      int b = tid/59, q = tid - b*59;
      cstore(&A_dw[(size_t)(r1+b)*320 + q], *(const unsigned*)&im[b*120 + 2*q]);
    }
#pragma unroll
    for (int k2=0;k2<4;++k2){
      int i3 = tid + k2*512;
      int b = i3 >> 8, q = i3 & 255;
      cstore(&A_dw[(size_t)(r1+b)*320 + 59 + q], *(const unsigned*)&hA[b*520 + 2*q]);
    }
    post_flag(&flags1[rg]);

    // ================= phase 2: rows r2..r2+64, units u0..u0+64 =================
    wait_flag(&flags1[rg], 8u*(unsigned)(t+1));

    f32x4 acc2[2][4];
#pragma unroll
    for (int i=0;i<2;++i)
#pragma unroll
      for (int g=0;g<4;++g) acc2[i][g] = (f32x4)(0.f);

    unsigned long long cAlo, cAhi, nAlo, nAhi;
    uint4 cB[4], nB[4];
    // prologue: stage 0 -> LDS buf0; issue stage 1 loads
    // NOTE: one stage = 64 bf16 cols = 32 dwords per row (stride fixed from r3's 16)
    {
      size_t d0 = (aRowBase + sc*4) >> 1;
      cAlo = cload64(&A64[d0]); cAhi = cload64(&A64[d0+1]);
#pragma unroll
      for (int p=0;p<4;++p) cB[p] = WgT4[ngBase[p]];
      uint4 av; av.x=(unsigned)cAlo; av.y=(unsigned)(cAlo>>32); av.z=(unsigned)cAhi; av.w=(unsigned)(cAhi>>32);
      ldsA[aDst] = av;
#pragma unroll
      for (int p=0;p<4;++p) ldsB[bDst[p]] = cB[p];
      size_t d1 = (aRowBase + 32 + sc*4) >> 1;
      cAlo = cload64(&A64[d1]); cAhi = cload64(&A64[d1+1]);
#pragma unroll
      for (int p=0;p<4;++p) cB[p] = WgT4[ngBase[p] + 8];
    }
    asm volatile("s_waitcnt lgkmcnt(0)" ::: "memory");
    __builtin_amdgcn_sched_barrier(0);
    __builtin_amdgcn_s_barrier();
    __builtin_amdgcn_sched_barrier(0);

#pragma unroll
    for (int s=0; s<10; ++s){
      if (s < 8){
        size_t dn = (aRowBase + (size_t)(s+2)*32 + sc*4) >> 1;
        nAlo = cload64(&A64[dn]); nAhi = cload64(&A64[dn+1]);
#pragma unroll
        for (int p=0;p<4;++p) nB[p] = WgT4[ngBase[p] + (size_t)(s+2)*8];
      }
      const int q = s & 1;
#pragma unroll
      for (int kk=0; kk<2; ++kk){
        bf16x8 af[2], bfr[4];
#pragma unroll
        for (int mf=0; mf<2; ++mf){
          int rr = rw2*32 + mf*16 + col;
          af[mf] = *(const bf16x8*)&ldsA[q*512 + rr*8 + ((kk*4+quad) ^ x7)];
        }
#pragma unroll
        for (int g=0; g<4; ++g){
          int n2 = g*64 + uh*16 + col;
          bfr[g] = *(const bf16x8*)&ldsB[q*2048 + n2*8 + ((kk*4+quad) ^ x7)];
        }
#pragma unroll
        for (int mf=0; mf<2; ++mf)
#pragma unroll
          for (int g=0; g<4; ++g)
            acc2[mf][g] = __builtin_amdgcn_mfma_f32_16x16x32_bf16(af[mf], bfr[g], acc2[mf][g], 0, 0, 0);
      }
      if (s < 9){
        const int nb = (s+1) & 1;
        uint4 av; av.x=(unsigned)cAlo; av.y=(unsigned)(cAlo>>32); av.z=(unsigned)cAhi; av.w=(unsigned)(cAhi>>32);
        ldsA[nb*512 + aDst] = av;
#pragma unroll
        for (int p=0;p<4;++p) ldsB[nb*2048 + bDst[p]] = cB[p];
        cAlo = nAlo; cAhi = nAhi;
#pragma unroll
        for (int p=0;p<4;++p) cB[p] = nB[p];
      }
      asm volatile("s_waitcnt lgkmcnt(0)" ::: "memory");
      __builtin_amdgcn_sched_barrier(0);
      __builtin_amdgcn_s_barrier();
      __builtin_amdgcn_sched_barrier(0);
    }

    // LSTM epilogue: c in regs; h(t) -> h_ws (coherent) + out_hid (streaming)
#pragma unroll
    for (int mf=0; mf<2; ++mf){
#pragma unroll
      for (int r=0; r<4; ++r){
        int b2 = r2 + rw2*32 + mf*16 + quad*4 + r;
        float gi = acc2[mf][0][r] + bi;
        float gf = acc2[mf][1][r] + bfv;
        float gg = acc2[mf][2][r] + bgv;
        float go = acc2[mf][3][r] + bov;
        float cn = sigf(gf)*creg[mf][r] + sigf(gi)*tanhf(gg);
        float hn = sigf(go)*tanhf(cn);
        creg[mf][r] = cn;
        cstoref(&h_ws[(size_t)b2*H_ + u2], hn);
        __builtin_nontemporal_store(hn, &out_hid[((size_t)b2*T_ + t)*H_ + u2]);
      }
    }
    post_flag(&flags2[rg]);
  }

  // final loss (block 0 after all rowgroups finished their t=47 phase-1 adds)
  if (blk == 0 && tid == 0){
    for (int i=0; i<RG_; ++i)
      while (cload(&flags1[i]) < 8u*T_) __builtin_amdgcn_s_sleep(2);
    float s = 0.f;
    for (int i=0; i<T_; ++i)
      s += cloadf(&loss_num[i]) / (cloadf(&loss_den[i]) + 1e-5f);
    *out_loss = s;
  }
}

extern "C" void kernel_launch(void* const* d_in, const int* in_sizes, int n_in,
                              void* d_out, int out_size, void* d_ws, size_t ws_size,
                              hipStream_t stream)
{
  const float* x      = (const float*)d_in[0];
  const float* mk     = (const float*)d_in[1];
  const float* dl     = (const float*)d_in[2];
  const float* W_gh   = (const float*)d_in[3];
  const float* b_gh   = (const float*)d_in[4];
  const float* w_gx   = (const float*)d_in[5];
  const float* b_gx   = (const float*)d_in[6];
  const float* W_hist = (const float*)d_in[7];
  const float* b_hist = (const float*)d_in[8];
  const float* W_fr   = (const float*)d_in[9];
  const float* b_fr   = (const float*)d_in[10];
  const float* W_wc   = (const float*)d_in[11];
  const float* b_wc   = (const float*)d_in[12];
  const float* W_ih   = (const float*)d_in[13];
  const float* W_hh   = (const float*)d_in[14];
  const float* b_ih   = (const float*)d_in[15];
  const float* b_hh   = (const float*)d_in[16];

  char* ws = (char*)d_ws;
  float*          h_ws  = (float*)(ws + OFF_H);
  float*          lnum  = (float*)(ws + OFF_LN);
  float*          lden  = (float*)(ws + OFF_LD);
  unsigned*       flg1  = (unsigned*)(ws + OFF_F1);
  unsigned*       flg2  = (unsigned*)(ws + OFF_F2);
  unsigned*       A_dw  = (unsigned*)(ws + OFF_A);
  unsigned short* WgT   = (unsigned short*)(ws + OFF_WGT);
  unsigned short* Wghb  = (unsigned short*)(ws + OFF_WGHB);
  unsigned short* WhB   = (unsigned short*)(ws + OFF_WHB);
  float*          WfrT  = (float*)(ws + OFF_WFR);
  float*          beta  = (float*)(ws + OFF_BETA);

  float* out      = (float*)d_out;
  float* out_ximp = out;                                   // [B,T,V]
  float* out_loss = out + (size_t)B_*T_*V_;                // scalar
  float* out_hid  = out + (size_t)B_*T_*V_ + 1;            // [B,T,H]

  hipMemsetAsync(d_ws, 0, MEMSET_BYTES, stream);           // h, loss, flags, A pads
  init_k<<<2048, 256, 0, stream>>>(W_gh, W_hist, W_fr, W_ih, W_hh,
                                   Wghb, WhB, WfrT, WgT);
  beta_k<<<(B_*T_)/4, 256, 0, stream>>>(mk, dl, w_gx, b_gx, W_wc, b_wc, beta, lden);
  fused<<<NBLK_, 512, 0, stream>>>(x, mk, dl, b_gh, b_hist, b_fr,
                                   Wghb, WhB, WfrT, beta, WgT, b_ih, b_hh,
                                   h_ws, A_dw, flg1, flg2, lnum, lden,
                                   out_ximp, out_hid, out_loss);
}